// Round 4
// baseline (379.326 us; speedup 1.0000x reference)
//
#include <hip/hip_runtime.h>
#include <stdint.h>
#include <stddef.h>

#define DIMN 2048
#define NH 16
#define HD 128
#define SEQ 2048
#define WIN 128   // mask: j - i > 128 is masked

typedef __attribute__((ext_vector_type(4))) float f32x4;
typedef __attribute__((ext_vector_type(8))) short bf16x8;
typedef __attribute__((ext_vector_type(4))) int i32x4;

#define AS1 __attribute__((address_space(1)))
#define AS3 __attribute__((address_space(3)))

__device__ __forceinline__ unsigned short f2bf(float f) {
  union { float f; unsigned u; } v; v.f = f;
  unsigned r = v.u + 0x7FFFu + ((v.u >> 16) & 1u);  // round-to-nearest-even
  return (unsigned short)(r >> 16);
}

// ---------------- cast f32 -> bf16 ----------------
__global__ void cast_bf16_kernel(const float* __restrict__ src,
                                 unsigned short* __restrict__ dst, int n4) {
  int i = blockIdx.x * blockDim.x + threadIdx.x;
  const int stride = gridDim.x * blockDim.x;
  for (; i < n4; i += stride) {
    float4 v = ((const float4*)src)[i];
    ushort4 o;
    o.x = f2bf(v.x); o.y = f2bf(v.y); o.z = f2bf(v.z); o.w = f2bf(v.w);
    ((ushort4*)dst)[i] = o;
  }
}

// fused cast of the 4 weight matrices (dst regions contiguous in ws)
__global__ void cast4_bf16_kernel(const float* __restrict__ s0, const float* __restrict__ s1,
                                  const float* __restrict__ s2, const float* __restrict__ s3,
                                  unsigned short* __restrict__ dst, int n4) {
  const float* s = (blockIdx.y == 0) ? s0 : (blockIdx.y == 1) ? s1 : (blockIdx.y == 2) ? s2 : s3;
  unsigned short* d = dst + (size_t)blockIdx.y * 4194304;
  int i = blockIdx.x * blockDim.x + threadIdx.x;
  const int stride = gridDim.x * blockDim.x;
  for (; i < n4; i += stride) {
    float4 v = ((const float4*)s)[i];
    ushort4 o;
    o.x = f2bf(v.x); o.y = f2bf(v.y); o.z = f2bf(v.z); o.w = f2bf(v.w);
    ((ushort4*)d)[i] = o;
  }
}

// ---------------- GEMM mainloop, m97-style (unchanged from R3) ----------------
__device__ __forceinline__ void gemm_mainloop_g128(
    const unsigned short* __restrict__ A, const unsigned short* __restrict__ B,
    int m0, int n0, unsigned short* As, unsigned short* Bs, f32x4 acc[4][4]) {
  const int t = threadIdx.x, lane = t & 63, wid = t >> 6;
  const int c = lane & 15, g = lane >> 4;
  const int wr = wid >> 1, wc = wid & 1;

  const int srow = wid * 32 + (lane >> 3);          // chunk base row (+(i*8))
  const int gslot = (lane & 7) ^ (lane >> 3);       // pre-swizzled global slot
  const unsigned short* ga = A + (size_t)(m0 + srow) * DIMN + gslot * 8;
  const unsigned short* gb = B + (size_t)(n0 + srow) * DIMN + gslot * 8;
  unsigned short* la = As + (size_t)(wid * 32) * 64;  // wave-uniform LDS base
  unsigned short* lb = Bs + (size_t)(wid * 32) * 64;

  const int swc = c & 7;  // read-side swizzle key

  for (int k0 = 0; k0 < DIMN; k0 += 64) {
    __syncthreads();  // previous K-tile's readers done
#pragma unroll
    for (int i = 0; i < 4; ++i) {
      __builtin_amdgcn_global_load_lds(
          (const AS1 unsigned*)(ga + (size_t)i * 8 * DIMN + k0),
          (AS3 unsigned*)(la + i * 8 * 64), 16, 0, 0);
      __builtin_amdgcn_global_load_lds(
          (const AS1 unsigned*)(gb + (size_t)i * 8 * DIMN + k0),
          (AS3 unsigned*)(lb + i * 8 * 64), 16, 0, 0);
    }
    __syncthreads();  // implicit vmcnt(0) drain -> LDS tile valid
#pragma unroll
    for (int kk = 0; kk < 2; ++kk) {
      bf16x8 af[4], bfv[4];
#pragma unroll
      for (int mi = 0; mi < 4; ++mi)
        af[mi] = *(const bf16x8*)&As[(wr * 64 + mi * 16 + c) * 64 +
                                     (((kk * 4 + g) ^ swc) * 8)];
#pragma unroll
      for (int ni = 0; ni < 4; ++ni)
        bfv[ni] = *(const bf16x8*)&Bs[(wc * 64 + ni * 16 + c) * 64 +
                                      (((kk * 4 + g) ^ swc) * 8)];
#pragma unroll
      for (int mi = 0; mi < 4; ++mi)
#pragma unroll
        for (int ni = 0; ni < 4; ++ni)
          acc[mi][ni] = __builtin_amdgcn_mfma_f32_16x16x32_bf16(
              af[mi], bfv[ni], acc[mi][ni], 0, 0, 0);
    }
  }
}

// ---------------- QKV projection (z: 0=Q, 1=K, 2=V-transposed) ----------------
__global__ __launch_bounds__(256, 3) void gemm_qkv_kernel(
    const unsigned short* __restrict__ Xb,
    const unsigned short* __restrict__ Wq,
    const unsigned short* __restrict__ Wk,
    const unsigned short* __restrict__ Wv,
    unsigned short* __restrict__ Qb,
    unsigned short* __restrict__ Kb,
    unsigned short* __restrict__ Vt) {
  __shared__ __attribute__((aligned(16))) unsigned short As[128 * 64];
  __shared__ __attribute__((aligned(16))) unsigned short Bs[128 * 64];
  const int z = blockIdx.z;
  const unsigned short* W = (z == 0) ? Wq : (z == 1) ? Wk : Wv;
  const int m0 = blockIdx.y * 128, n0 = blockIdx.x * 128;

  f32x4 acc[4][4];
  const f32x4 zv = {0.f, 0.f, 0.f, 0.f};
#pragma unroll
  for (int i = 0; i < 4; ++i)
#pragma unroll
    for (int j = 0; j < 4; ++j) acc[i][j] = zv;

  gemm_mainloop_g128(Xb, W, m0, n0, As, Bs, acc);

  const int lane = threadIdx.x & 63, wid = threadIdx.x >> 6;
  const int c = lane & 15, g = lane >> 4;
  const int wr = wid >> 1, wc = wid & 1;
  unsigned short* Out01 = (z == 0) ? Qb : Kb;
#pragma unroll
  for (int mi = 0; mi < 4; ++mi) {
#pragma unroll
    for (int ni = 0; ni < 4; ++ni) {
      const int mrow = m0 + wr * 64 + mi * 16 + g * 4;  // m = b*SEQ + s
      const int ncol = n0 + wc * 64 + ni * 16 + c;      // n = h*HD + d
      const int h = ncol >> 7, d = ncol & 127;
      const int b = mrow >> 11, s = mrow & 2047;
      if (z < 2) {
#pragma unroll
        for (int j = 0; j < 4; ++j)
          Out01[((size_t)(b * NH + h) * SEQ + s + j) * HD + d] =
              f2bf(acc[mi][ni][j]);
      } else {
        ushort4 pk;
        pk.x = f2bf(acc[mi][ni][0]); pk.y = f2bf(acc[mi][ni][1]);
        pk.z = f2bf(acc[mi][ni][2]); pk.w = f2bf(acc[mi][ni][3]);
        *(ushort4*)&Vt[((size_t)(b * NH + h) * HD + d) * SEQ + s] = pk;
      }
    }
  }
}

// ---------------- output projection: f32 out ----------------
__global__ __launch_bounds__(256, 3) void gemm_out_kernel(
    const unsigned short* __restrict__ Ab,
    const unsigned short* __restrict__ Wo,
    float* __restrict__ Cf) {
  __shared__ __attribute__((aligned(16))) unsigned short As[128 * 64];
  __shared__ __attribute__((aligned(16))) unsigned short Bs[128 * 64];
  const int m0 = blockIdx.y * 128, n0 = blockIdx.x * 128;

  f32x4 acc[4][4];
  const f32x4 zv = {0.f, 0.f, 0.f, 0.f};
#pragma unroll
  for (int i = 0; i < 4; ++i)
#pragma unroll
    for (int j = 0; j < 4; ++j) acc[i][j] = zv;

  gemm_mainloop_g128(Ab, Wo, m0, n0, As, Bs, acc);

  const int lane = threadIdx.x & 63, wid = threadIdx.x >> 6;
  const int c = lane & 15, g = lane >> 4;
  const int wr = wid >> 1, wc = wid & 1;
#pragma unroll
  for (int mi = 0; mi < 4; ++mi) {
#pragma unroll
    for (int ni = 0; ni < 4; ++ni) {
      const int mrow = m0 + wr * 64 + mi * 16 + g * 4;
      const int ncol = n0 + wc * 64 + ni * 16 + c;
#pragma unroll
      for (int j = 0; j < 4; ++j)
        Cf[(size_t)(mrow + j) * DIMN + ncol] = acc[mi][ni][j];
    }
  }
}

// ---------------- flash attention v3: double-buffered, 1 barrier/iter ----------------
// 128 q-rows per block (4 waves x 32 rows), KV tile = 64.
// K[2][64][128], V^T[2][128][64] double-buffered; P[4][32][64]; all XOR-swizzled.
// Iter tt: ds_write tile tt+1 -> buf^1 (overlaps MFMA on buf), issue loads tt+2,
// compute, ONE barrier. L row-sum reduce deferred to epilogue (linear in rescale).
__global__ __launch_bounds__(256, 2) void attn_kernel(
    const unsigned short* __restrict__ Qg,
    const unsigned short* __restrict__ Kg,
    const unsigned short* __restrict__ Vtg,
    unsigned short* __restrict__ Og) {
  __shared__ __attribute__((aligned(16))) unsigned short Ks[2][64 * 128];
  __shared__ __attribute__((aligned(16))) unsigned short Vs[2][128 * 64];
  __shared__ __attribute__((aligned(16))) unsigned short Ps[4 * 32 * 64];

  const int bh = blockIdx.x;
  const int yy = blockIdx.y;
  const int qt = (yy < 8) ? yy : 23 - yy;  // qt(y) + qt(y+8) == 15 (CU balance)
  const int q0 = qt * 128;
  const int t = threadIdx.x, wid = t >> 6, lane = t & 63;
  const int c = lane & 15, g = lane >> 4;
  const int swc = c & 7;  // swizzle key for reads (row&7 == c&7 for our rows)

  const unsigned short* Kbh = Kg + (size_t)bh * SEQ * HD;
  const unsigned short* Vbh = Vtg + (size_t)bh * HD * SEQ;

  // Q fragments: rows q0 + wid*32 + mi*16 + c ; k = kk*32 + g*8
  bf16x8 qf[2][4];
#pragma unroll
  for (int mi = 0; mi < 2; ++mi) {
    const unsigned short* qb =
        Qg + ((size_t)bh * SEQ + q0 + wid * 32 + mi * 16 + c) * HD + g * 8;
#pragma unroll
    for (int kk = 0; kk < 4; ++kk) qf[mi][kk] = *(const bf16x8*)(qb + kk * 32);
  }

  f32x4 o[2][8];
  const f32x4 zv = {0.f, 0.f, 0.f, 0.f};
#pragma unroll
  for (int mi = 0; mi < 2; ++mi)
#pragma unroll
    for (int ni = 0; ni < 8; ++ni) o[mi][ni] = zv;
  float M[2][4], L[2][4];  // L = per-lane PARTIAL row sums (reduced at epilogue)
#pragma unroll
  for (int mi = 0; mi < 2; ++mi)
#pragma unroll
    for (int j = 0; j < 4; ++j) { M[mi][j] = -1e30f; L[mi][j] = 0.f; }

  const int ntA = (q0 + 256) >> 6;
  const int nt = (ntA < (SEQ >> 6)) ? ntA : (SEQ >> 6);
  const float kl2e = 0.08838834764831845f * 1.4426950408889634f;  // scale*log2(e)

  // staging geometry (per thread, loop-invariant)
  const int kswz = (t & 15) ^ ((t >> 4) & 7);
  const int vswz = (t & 7) ^ ((t >> 3) & 7);
  const int kgo = (t >> 4) * HD + (t & 15) * 8;            // K global offset within tile
  const int klo = (t >> 4) * 128 + kswz * 8;               // K LDS offset
  const int vlo = (t >> 3) * 64 + vswz * 8;                // V LDS offset
  const size_t vgo = (size_t)(t >> 3) * SEQ + (t & 7) * 8; // V global offset

  i32x4 kc[4], vc[4];
#pragma unroll
  for (int r = 0; r < 4; ++r) {  // tile 0
    kc[r] = *(const i32x4*)(Kbh + (size_t)r * 16 * HD + kgo);
    vc[r] = *(const i32x4*)(Vbh + (size_t)r * 32 * SEQ + vgo);
  }
#pragma unroll
  for (int r = 0; r < 4; ++r) {  // stage tile 0 -> buf0
    *(i32x4*)&Ks[0][r * 2048 + klo] = kc[r];
    *(i32x4*)&Vs[0][r * 2048 + vlo] = vc[r];
  }
  if (nt > 1) {  // tile 1 -> regs
#pragma unroll
    for (int r = 0; r < 4; ++r) {
      kc[r] = *(const i32x4*)(Kbh + (size_t)(64 + r * 16) * HD + kgo);
      vc[r] = *(const i32x4*)(Vbh + (size_t)r * 32 * SEQ + 64 + vgo);
    }
  }
  __syncthreads();

  int cur = 0;
  for (int tt = 0; tt < nt; ++tt) {
    const int j0 = tt * 64;
    if (tt + 1 < nt) {
      // stage tile tt+1 into the other buffer (overlaps this iter's MFMA)
#pragma unroll
      for (int r = 0; r < 4; ++r) {
        *(i32x4*)&Ks[cur ^ 1][r * 2048 + klo] = kc[r];
        *(i32x4*)&Vs[cur ^ 1][r * 2048 + vlo] = vc[r];
      }
      if (tt + 2 < nt) {  // issue loads for tile tt+2
        const int j2 = j0 + 128;
#pragma unroll
        for (int r = 0; r < 4; ++r) {
          kc[r] = *(const i32x4*)(Kbh + (size_t)(j2 + r * 16) * HD + kgo);
          vc[r] = *(const i32x4*)(Vbh + (size_t)r * 32 * SEQ + j2 + vgo);
        }
      }
    }
    const unsigned short* Kc = Ks[cur];
    const unsigned short* Vc = Vs[cur];

    // QK^T: 32 rows x 64 cols per wave; sc[mi][ni]: rows mi*16+4g+j, col 16ni+c
    f32x4 sc[2][4];
#pragma unroll
    for (int mi = 0; mi < 2; ++mi)
#pragma unroll
      for (int ni = 0; ni < 4; ++ni) sc[mi][ni] = zv;
    __builtin_amdgcn_s_setprio(1);
#pragma unroll
    for (int kk = 0; kk < 4; ++kk) {
#pragma unroll
      for (int ni = 0; ni < 4; ++ni) {
        const bf16x8 kf =
            *(const bf16x8*)&Kc[(ni * 16 + c) * 128 + ((kk * 4 + g) ^ swc) * 8];
        sc[0][ni] = __builtin_amdgcn_mfma_f32_16x16x32_bf16(qf[0][kk], kf, sc[0][ni], 0, 0, 0);
        sc[1][ni] = __builtin_amdgcn_mfma_f32_16x16x32_bf16(qf[1][kk], kf, sc[1][ni], 0, 0, 0);
      }
    }
    __builtin_amdgcn_s_setprio(0);

    // masking: only tiles with j0 >= q0+128 can contain masked elements
    if (j0 - q0 >= 128) {
#pragma unroll
      for (int mi = 0; mi < 2; ++mi)
#pragma unroll
        for (int ni = 0; ni < 4; ++ni) {
          const int jg = j0 + ni * 16 + c;
#pragma unroll
          for (int j = 0; j < 4; ++j) {
            const int ig = q0 + wid * 32 + mi * 16 + g * 4 + j;
            if (jg > ig + WIN) sc[mi][ni][j] = -3.0e38f;
          }
        }
    }

    // row maxima (rows live in 16-lane groups sharing g; xor<16 stays in group)
    float tmax[2][4], dmax = -3.0e38f;
#pragma unroll
    for (int mi = 0; mi < 2; ++mi)
#pragma unroll
      for (int j = 0; j < 4; ++j) {
        float mx = fmaxf(fmaxf(sc[mi][0][j], sc[mi][1][j]),
                         fmaxf(sc[mi][2][j], sc[mi][3][j]));
        mx = fmaxf(mx, __shfl_xor(mx, 1));
        mx = fmaxf(mx, __shfl_xor(mx, 2));
        mx = fmaxf(mx, __shfl_xor(mx, 4));
        mx = fmaxf(mx, __shfl_xor(mx, 8));
        tmax[mi][j] = mx;
        dmax = fmaxf(dmax, mx - M[mi][j]);
      }
    // defer-max (T13): rescale only when tile max exceeds running max by >64
    // unscaled logits (64*scale*log2e = 8.2 -> P <= 2^8.2, safe in bf16/f32)
    if (__any(dmax > 64.f)) {
#pragma unroll
      for (int mi = 0; mi < 2; ++mi)
#pragma unroll
        for (int j = 0; j < 4; ++j) {
          const float nm = fmaxf(M[mi][j], tmax[mi][j]);
          const float al = __builtin_amdgcn_exp2f((M[mi][j] - nm) * kl2e);
          M[mi][j] = nm;
          L[mi][j] *= al;  // partial sums scale linearly
#pragma unroll
          for (int ni = 0; ni < 8; ++ni) o[mi][ni][j] *= al;
        }
    }

    // P = exp(sc - M), bf16, swizzled into per-wave LDS; accumulate PARTIAL sums
#pragma unroll
    for (int mi = 0; mi < 2; ++mi) {
      float rs0 = 0.f, rs1 = 0.f, rs2 = 0.f, rs3 = 0.f;
#pragma unroll
      for (int ni = 0; ni < 4; ++ni)
#pragma unroll
        for (int j = 0; j < 4; ++j) {
          const float p = __builtin_amdgcn_exp2f((sc[mi][ni][j] - M[mi][j]) * kl2e);
          if (j == 0) rs0 += p; else if (j == 1) rs1 += p;
          else if (j == 2) rs2 += p; else rs3 += p;
          const int prow = mi * 16 + g * 4 + j;
          Ps[wid * 2048 + prow * 64 + ((2 * ni + (c >> 3)) ^ (prow & 7)) * 8 + (c & 7)] =
              f2bf(p);
        }
      L[mi][0] += rs0; L[mi][1] += rs1; L[mi][2] += rs2; L[mi][3] += rs3;
    }

    // PV: P(32x64) x V^T ; per-wave Ps, no barrier needed (same-wave write/read)
    __builtin_amdgcn_s_setprio(1);
#pragma unroll
    for (int kk2 = 0; kk2 < 2; ++kk2) {
      bf16x8 pf[2];
#pragma unroll
      for (int mi = 0; mi < 2; ++mi)
        pf[mi] = *(const bf16x8*)&Ps[wid * 2048 + (mi * 16 + c) * 64 +
                                     ((kk2 * 4 + g) ^ swc) * 8];
#pragma unroll
      for (int ni = 0; ni < 8; ++ni) {
        const bf16x8 vf =
            *(const bf16x8*)&Vc[(ni * 16 + c) * 64 + ((kk2 * 4 + g) ^ swc) * 8];
        o[0][ni] = __builtin_amdgcn_mfma_f32_16x16x32_bf16(pf[0], vf, o[0][ni], 0, 0, 0);
        o[1][ni] = __builtin_amdgcn_mfma_f32_16x16x32_bf16(pf[1], vf, o[1][ni], 0, 0, 0);
      }
    }
    __builtin_amdgcn_s_setprio(0);

    __syncthreads();  // single barrier: buf^1 writes visible, buf readers done
    cur ^= 1;
  }

  // epilogue: reduce partial L across the 16-lane group, normalize, store
  const int b = bh >> 4, h = bh & 15;
#pragma unroll
  for (int mi = 0; mi < 2; ++mi)
#pragma unroll
    for (int j = 0; j < 4; ++j) {
      float s = L[mi][j];
      s += __shfl_xor(s, 1);
      s += __shfl_xor(s, 2);
      s += __shfl_xor(s, 4);
      s += __shfl_xor(s, 8);
      const float inv = 1.0f / s;
      const int srow = q0 + wid * 32 + mi * 16 + g * 4 + j;
      unsigned short* orow = Og + (size_t)(b * SEQ + srow) * DIMN + h * HD;
#pragma unroll
      for (int ni = 0; ni < 8; ++ni) orow[ni * 16 + c] = f2bf(o[mi][ni][j] * inv);
    }
}

// ---------------- launch ----------------
extern "C" void kernel_launch(void* const* d_in, const int* in_sizes, int n_in,
                              void* d_out, int out_size, void* d_ws, size_t ws_size,
                              hipStream_t stream) {
  (void)in_sizes; (void)n_in; (void)out_size; (void)ws_size;
  const float* x  = (const float*)d_in[0];
  const float* wq = (const float*)d_in[1];
  const float* wk = (const float*)d_in[2];
  const float* wv = (const float*)d_in[3];
  const float* wo = (const float*)d_in[4];
  float* out = (float*)d_out;

  // workspace layout (bf16 elems); total ~112 MB
  unsigned short* xb  = (unsigned short*)d_ws;          // 4096x2048
  unsigned short* wqb = xb  + (size_t)8388608;          // 2048x2048 each, contiguous
  unsigned short* wkb = wqb + (size_t)4194304;
  unsigned short* wvb = wkb + (size_t)4194304;
  unsigned short* wob = wvb + (size_t)4194304;
  unsigned short* Qb  = wob + (size_t)4194304;          // (B,H,S,D)
  unsigned short* Kb  = Qb  + (size_t)8388608;          // (B,H,S,D)
  unsigned short* Vt  = Kb  + (size_t)8388608;          // (B,H,D,S)
  unsigned short* Ab  = Vt  + (size_t)8388608;          // (B*S, DIM)

  cast_bf16_kernel<<<dim3(1024), dim3(256), 0, stream>>>(x, xb, 2097152);
  cast4_bf16_kernel<<<dim3(512, 4), dim3(256), 0, stream>>>(wq, wk, wv, wo, wqb, 1048576);

  gemm_qkv_kernel<<<dim3(16, 32, 3), dim3(256), 0, stream>>>(xb, wqb, wkb, wvb, Qb, Kb, Vt);
  attn_kernel<<<dim3(32, 16), dim3(256), 0, stream>>>(Qb, Kb, Vt, Ab);
  gemm_out_kernel<<<dim3(16, 32), dim3(256), 0, stream>>>(Ab, wob, out);
}

// Round 5
// 345.471 us; speedup vs baseline: 1.0980x; 1.0980x over previous
//
#include <hip/hip_runtime.h>
#include <stdint.h>
#include <stddef.h>

#define DIMN 2048
#define NH 16
#define HD 128
#define SEQ 2048
#define WIN 128   // mask: j - i > 128 is masked

typedef __attribute__((ext_vector_type(4))) float f32x4;
typedef __attribute__((ext_vector_type(8))) short bf16x8;
typedef __attribute__((ext_vector_type(4))) int i32x4;

#define AS1 __attribute__((address_space(1)))
#define AS3 __attribute__((address_space(3)))

__device__ __forceinline__ unsigned short f2bf(float f) {
  union { float f; unsigned u; } v; v.f = f;
  unsigned r = v.u + 0x7FFFu + ((v.u >> 16) & 1u);  // round-to-nearest-even
  return (unsigned short)(r >> 16);
}

// ---------------- fused cast: x (2 slices) + 4 weights -> contiguous bf16 ws ----------------
__global__ void cast_all_kernel(const float* __restrict__ x,
                                const float* __restrict__ wq, const float* __restrict__ wk,
                                const float* __restrict__ wv, const float* __restrict__ wo,
                                unsigned short* __restrict__ dst) {
  const int y = blockIdx.y;
  const float* s;
  if (y < 2) s = x + (size_t)y * 4194304;
  else if (y == 2) s = wq;
  else if (y == 3) s = wk;
  else if (y == 4) s = wv;
  else s = wo;
  ushort4* d = (ushort4*)dst + (size_t)y * 1048576;
  int i = blockIdx.x * blockDim.x + threadIdx.x;
  const int stride = gridDim.x * blockDim.x;
  for (; i < 1048576; i += stride) {
    float4 v = ((const float4*)s)[i];
    ushort4 o;
    o.x = f2bf(v.x); o.y = f2bf(v.y); o.z = f2bf(v.z); o.w = f2bf(v.w);
    d[i] = o;
  }
}

// ---------------- GEMM mainloop, m97-style (unchanged from R4: conflicts=0, ~983 TF) ----------------
__device__ __forceinline__ void gemm_mainloop_g128(
    const unsigned short* __restrict__ A, const unsigned short* __restrict__ B,
    int m0, int n0, unsigned short* As, unsigned short* Bs, f32x4 acc[4][4]) {
  const int t = threadIdx.x, lane = t & 63, wid = t >> 6;
  const int c = lane & 15, g = lane >> 4;
  const int wr = wid >> 1, wc = wid & 1;

  const int srow = wid * 32 + (lane >> 3);          // chunk base row (+(i*8))
  const int gslot = (lane & 7) ^ (lane >> 3);       // pre-swizzled global slot
  const unsigned short* ga = A + (size_t)(m0 + srow) * DIMN + gslot * 8;
  const unsigned short* gb = B + (size_t)(n0 + srow) * DIMN + gslot * 8;
  unsigned short* la = As + (size_t)(wid * 32) * 64;  // wave-uniform LDS base
  unsigned short* lb = Bs + (size_t)(wid * 32) * 64;

  const int swc = c & 7;  // read-side swizzle key

  for (int k0 = 0; k0 < DIMN; k0 += 64) {
    __syncthreads();  // previous K-tile's readers done
#pragma unroll
    for (int i = 0; i < 4; ++i) {
      __builtin_amdgcn_global_load_lds(
          (const AS1 unsigned*)(ga + (size_t)i * 8 * DIMN + k0),
          (AS3 unsigned*)(la + i * 8 * 64), 16, 0, 0);
      __builtin_amdgcn_global_load_lds(
          (const AS1 unsigned*)(gb + (size_t)i * 8 * DIMN + k0),
          (AS3 unsigned*)(lb + i * 8 * 64), 16, 0, 0);
    }
    __syncthreads();  // implicit vmcnt(0) drain -> LDS tile valid
#pragma unroll
    for (int kk = 0; kk < 2; ++kk) {
      bf16x8 af[4], bfv[4];
#pragma unroll
      for (int mi = 0; mi < 4; ++mi)
        af[mi] = *(const bf16x8*)&As[(wr * 64 + mi * 16 + c) * 64 +
                                     (((kk * 4 + g) ^ swc) * 8)];
#pragma unroll
      for (int ni = 0; ni < 4; ++ni)
        bfv[ni] = *(const bf16x8*)&Bs[(wc * 64 + ni * 16 + c) * 64 +
                                      (((kk * 4 + g) ^ swc) * 8)];
#pragma unroll
      for (int mi = 0; mi < 4; ++mi)
#pragma unroll
        for (int ni = 0; ni < 4; ++ni)
          acc[mi][ni] = __builtin_amdgcn_mfma_f32_16x16x32_bf16(
              af[mi], bfv[ni], acc[mi][ni], 0, 0, 0);
    }
  }
}

// ---------------- QKV projection (z: 0=Q, 1=K, 2=V-transposed) ----------------
__global__ __launch_bounds__(256, 3) void gemm_qkv_kernel(
    const unsigned short* __restrict__ Xb,
    const unsigned short* __restrict__ Wq,
    const unsigned short* __restrict__ Wk,
    const unsigned short* __restrict__ Wv,
    unsigned short* __restrict__ Qb,
    unsigned short* __restrict__ Kb,
    unsigned short* __restrict__ Vt) {
  __shared__ __attribute__((aligned(16))) unsigned short As[128 * 64];
  __shared__ __attribute__((aligned(16))) unsigned short Bs[128 * 64];
  const int z = blockIdx.z;
  const unsigned short* W = (z == 0) ? Wq : (z == 1) ? Wk : Wv;
  const int m0 = blockIdx.y * 128, n0 = blockIdx.x * 128;

  f32x4 acc[4][4];
  const f32x4 zv = {0.f, 0.f, 0.f, 0.f};
#pragma unroll
  for (int i = 0; i < 4; ++i)
#pragma unroll
    for (int j = 0; j < 4; ++j) acc[i][j] = zv;

  gemm_mainloop_g128(Xb, W, m0, n0, As, Bs, acc);

  const int lane = threadIdx.x & 63, wid = threadIdx.x >> 6;
  const int c = lane & 15, g = lane >> 4;
  const int wr = wid >> 1, wc = wid & 1;
  unsigned short* Out01 = (z == 0) ? Qb : Kb;
#pragma unroll
  for (int mi = 0; mi < 4; ++mi) {
#pragma unroll
    for (int ni = 0; ni < 4; ++ni) {
      const int mrow = m0 + wr * 64 + mi * 16 + g * 4;  // m = b*SEQ + s
      const int ncol = n0 + wc * 64 + ni * 16 + c;      // n = h*HD + d
      const int h = ncol >> 7, d = ncol & 127;
      const int b = mrow >> 11, s = mrow & 2047;
      if (z < 2) {
#pragma unroll
        for (int j = 0; j < 4; ++j)
          Out01[((size_t)(b * NH + h) * SEQ + s + j) * HD + d] =
              f2bf(acc[mi][ni][j]);
      } else {
        ushort4 pk;
        pk.x = f2bf(acc[mi][ni][0]); pk.y = f2bf(acc[mi][ni][1]);
        pk.z = f2bf(acc[mi][ni][2]); pk.w = f2bf(acc[mi][ni][3]);
        *(ushort4*)&Vt[((size_t)(b * NH + h) * HD + d) * SEQ + s] = pk;
      }
    }
  }
}

// ---------------- output projection: f32 out ----------------
__global__ __launch_bounds__(256, 3) void gemm_out_kernel(
    const unsigned short* __restrict__ Ab,
    const unsigned short* __restrict__ Wo,
    float* __restrict__ Cf) {
  __shared__ __attribute__((aligned(16))) unsigned short As[128 * 64];
  __shared__ __attribute__((aligned(16))) unsigned short Bs[128 * 64];
  const int m0 = blockIdx.y * 128, n0 = blockIdx.x * 128;

  f32x4 acc[4][4];
  const f32x4 zv = {0.f, 0.f, 0.f, 0.f};
#pragma unroll
  for (int i = 0; i < 4; ++i)
#pragma unroll
    for (int j = 0; j < 4; ++j) acc[i][j] = zv;

  gemm_mainloop_g128(Ab, Wo, m0, n0, As, Bs, acc);

  const int lane = threadIdx.x & 63, wid = threadIdx.x >> 6;
  const int c = lane & 15, g = lane >> 4;
  const int wr = wid >> 1, wc = wid & 1;
#pragma unroll
  for (int mi = 0; mi < 4; ++mi) {
#pragma unroll
    for (int ni = 0; ni < 4; ++ni) {
      const int mrow = m0 + wr * 64 + mi * 16 + g * 4;
      const int ncol = n0 + wc * 64 + ni * 16 + c;
#pragma unroll
      for (int j = 0; j < 4; ++j)
        Cf[(size_t)(mrow + j) * DIMN + ncol] = acc[mi][ni][j];
    }
  }
}

// ---------------- flash attention v4: swapped QK^T, in-lane softmax ----------------
// 128 q-rows per block (4 waves x 32 rows), KV tile = 64, K/V double-buffered.
// QK^T computed as mfma(K, Q) -> lane holds 16 scores of ONE q-row:
//   sc[mi][ni][j] = S[key = j0+16ni+4g+j][q = q0+wid*32+mi*16+c]
// Row-max: 15 in-lane fmax + 2 shfl (vs 32 shfls before). Row-sum: per-lane
// partial, reduced once in epilogue. P bounced through per-wave LDS [q][key]
// (16B-slot XOR swizzle), consumed as B-operand of mfma(V^T, P).
__global__ __launch_bounds__(256, 2) void attn_kernel(
    const unsigned short* __restrict__ Qg,
    const unsigned short* __restrict__ Kg,
    const unsigned short* __restrict__ Vtg,
    unsigned short* __restrict__ Og) {
  __shared__ __attribute__((aligned(16))) unsigned short Ks[2][64 * 128];
  __shared__ __attribute__((aligned(16))) unsigned short Vs[2][128 * 64];
  __shared__ __attribute__((aligned(16))) unsigned short Ps[4 * 32 * 64];

  const int bh = blockIdx.x;
  const int yy = blockIdx.y;
  const int qt = (yy < 8) ? yy : 23 - yy;  // co-resident pair (yy, yy+8) -> qt+qt' = 15
  const int q0 = qt * 128;
  const int t = threadIdx.x, wid = t >> 6, lane = t & 63;
  const int c = lane & 15, g = lane >> 4;
  const int swc = c & 7;

  const unsigned short* Kbh = Kg + (size_t)bh * SEQ * HD;
  const unsigned short* Vbh = Vtg + (size_t)bh * HD * SEQ;

  // Q fragments: rows q0 + wid*32 + mi*16 + c ; k = kk*32 + g*8 (B-operand now)
  bf16x8 qf[2][4];
#pragma unroll
  for (int mi = 0; mi < 2; ++mi) {
    const unsigned short* qb =
        Qg + ((size_t)bh * SEQ + q0 + wid * 32 + mi * 16 + c) * HD + g * 8;
#pragma unroll
    for (int kk = 0; kk < 4; ++kk) qf[mi][kk] = *(const bf16x8*)(qb + kk * 32);
  }

  // o[mi][ni][j] = O[q = mi*16+c][d = ni*16 + 4g + j]
  f32x4 o[2][8];
  const f32x4 zv = {0.f, 0.f, 0.f, 0.f};
#pragma unroll
  for (int mi = 0; mi < 2; ++mi)
#pragma unroll
    for (int ni = 0; ni < 8; ++ni) o[mi][ni] = zv;
  float M[2] = {-1e30f, -1e30f};  // running max per q-row (this lane's row)
  float L[2] = {0.f, 0.f};        // per-lane PARTIAL row sums

  const int ntA = (q0 + 256) >> 6;
  const int nt = (ntA < (SEQ >> 6)) ? ntA : (SEQ >> 6);
  const float kl2e = 0.08838834764831845f * 1.4426950408889634f;  // scale*log2(e)

  // staging geometry (per thread, loop-invariant)
  const int kswz = (t & 15) ^ ((t >> 4) & 7);
  const int vswz = (t & 7) ^ ((t >> 3) & 7);
  const int kgo = (t >> 4) * HD + (t & 15) * 8;
  const int klo = (t >> 4) * 128 + kswz * 8;
  const int vlo = (t >> 3) * 64 + vswz * 8;
  const size_t vgo = (size_t)(t >> 3) * SEQ + (t & 7) * 8;

  i32x4 kc[4], vc[4];
#pragma unroll
  for (int r = 0; r < 4; ++r) {  // tile 0
    kc[r] = *(const i32x4*)(Kbh + (size_t)r * 16 * HD + kgo);
    vc[r] = *(const i32x4*)(Vbh + (size_t)r * 32 * SEQ + vgo);
  }
#pragma unroll
  for (int r = 0; r < 4; ++r) {  // stage tile 0 -> buf0
    *(i32x4*)&Ks[0][r * 2048 + klo] = kc[r];
    *(i32x4*)&Vs[0][r * 2048 + vlo] = vc[r];
  }
  if (nt > 1) {  // tile 1 -> regs
#pragma unroll
    for (int r = 0; r < 4; ++r) {
      kc[r] = *(const i32x4*)(Kbh + (size_t)(64 + r * 16) * HD + kgo);
      vc[r] = *(const i32x4*)(Vbh + (size_t)r * 32 * SEQ + 64 + vgo);
    }
  }
  __syncthreads();

  int cur = 0;
  for (int tt = 0; tt < nt; ++tt) {
    const int j0 = tt * 64;
    if (tt + 1 < nt) {
#pragma unroll
      for (int r = 0; r < 4; ++r) {
        *(i32x4*)&Ks[cur ^ 1][r * 2048 + klo] = kc[r];
        *(i32x4*)&Vs[cur ^ 1][r * 2048 + vlo] = vc[r];
      }
      if (tt + 2 < nt) {
        const int j2 = j0 + 128;
#pragma unroll
        for (int r = 0; r < 4; ++r) {
          kc[r] = *(const i32x4*)(Kbh + (size_t)(j2 + r * 16) * HD + kgo);
          vc[r] = *(const i32x4*)(Vbh + (size_t)r * 32 * SEQ + j2 + vgo);
        }
      }
    }
    const unsigned short* Kc = Ks[cur];
    const unsigned short* Vc = Vs[cur];

    // QK^T swapped: sc[mi][ni] cols = q (mi*16+c), rows = key (16ni+4g+j)
    f32x4 sc[2][4];
#pragma unroll
    for (int mi = 0; mi < 2; ++mi)
#pragma unroll
      for (int ni = 0; ni < 4; ++ni) sc[mi][ni] = zv;
    __builtin_amdgcn_s_setprio(1);
#pragma unroll
    for (int kk = 0; kk < 4; ++kk) {
#pragma unroll
      for (int ni = 0; ni < 4; ++ni) {
        const bf16x8 kf =
            *(const bf16x8*)&Kc[(ni * 16 + c) * 128 + ((kk * 4 + g) ^ swc) * 8];
        sc[0][ni] = __builtin_amdgcn_mfma_f32_16x16x32_bf16(kf, qf[0][kk], sc[0][ni], 0, 0, 0);
        sc[1][ni] = __builtin_amdgcn_mfma_f32_16x16x32_bf16(kf, qf[1][kk], sc[1][ni], 0, 0, 0);
      }
    }
    __builtin_amdgcn_s_setprio(0);

    // masking: key jg = j0+16ni+4g+j vs q ig = q0+wid*32+mi*16+c
    if (j0 - q0 >= 128) {
#pragma unroll
      for (int mi = 0; mi < 2; ++mi) {
        const int ig = q0 + wid * 32 + mi * 16 + c;
#pragma unroll
        for (int ni = 0; ni < 4; ++ni) {
#pragma unroll
          for (int j = 0; j < 4; ++j) {
            const int jg = j0 + ni * 16 + g * 4 + j;
            if (jg > ig + WIN) sc[mi][ni][j] = -3.0e38f;
          }
        }
      }
    }

    // in-lane row max (15 fmax) + 2 shfls across the g-groups
    float tmax[2];
#pragma unroll
    for (int mi = 0; mi < 2; ++mi) {
      float m0v = fmaxf(fmaxf(sc[mi][0][0], sc[mi][0][1]), fmaxf(sc[mi][0][2], sc[mi][0][3]));
      float m1v = fmaxf(fmaxf(sc[mi][1][0], sc[mi][1][1]), fmaxf(sc[mi][1][2], sc[mi][1][3]));
      float m2v = fmaxf(fmaxf(sc[mi][2][0], sc[mi][2][1]), fmaxf(sc[mi][2][2], sc[mi][2][3]));
      float m3v = fmaxf(fmaxf(sc[mi][3][0], sc[mi][3][1]), fmaxf(sc[mi][3][2], sc[mi][3][3]));
      float mx = fmaxf(fmaxf(m0v, m1v), fmaxf(m2v, m3v));
      mx = fmaxf(mx, __shfl_xor(mx, 16));
      mx = fmaxf(mx, __shfl_xor(mx, 32));
      tmax[mi] = mx;
    }
    const float dmax = fmaxf(tmax[0] - M[0], tmax[1] - M[1]);
    // defer-max (T13): rescale only when tile max exceeds running max by >64
    if (__any(dmax > 64.f)) {
#pragma unroll
      for (int mi = 0; mi < 2; ++mi) {
        const float nm = fmaxf(M[mi], tmax[mi]);
        const float al = __builtin_amdgcn_exp2f((M[mi] - nm) * kl2e);
        M[mi] = nm;
        L[mi] *= al;
#pragma unroll
        for (int ni = 0; ni < 8; ++ni) o[mi][ni] *= al;
      }
    }

    // P = exp(sc - M): per-lane partial sums; vectorized swizzled LDS write.
    // Ps row q' = mi*16+c (64 elems); elem col 16ni+4g -> 16B slot (2ni+(g>>1))^(c&7)
#pragma unroll
    for (int mi = 0; mi < 2; ++mi) {
      float rs = 0.f;
#pragma unroll
      for (int ni = 0; ni < 4; ++ni) {
        ushort4 pk;
#pragma unroll
        for (int j = 0; j < 4; ++j) {
          const float p = __builtin_amdgcn_exp2f((sc[mi][ni][j] - M[mi]) * kl2e);
          rs += p;
          ((unsigned short*)&pk)[j] = f2bf(p);
        }
        *(ushort4*)&Ps[wid * 2048 + (mi * 16 + c) * 64 +
                       ((2 * ni + (g >> 1)) ^ swc) * 8 + (g & 1) * 4] = pk;
      }
      L[mi] += rs;
    }

    // PV: o = V^T x P  (A = V^T frag, B = P frag; per-wave Ps, same-wave r/w)
    __builtin_amdgcn_s_setprio(1);
#pragma unroll
    for (int kk2 = 0; kk2 < 2; ++kk2) {
      bf16x8 pf[2];
#pragma unroll
      for (int mi = 0; mi < 2; ++mi)
        pf[mi] = *(const bf16x8*)&Ps[wid * 2048 + (mi * 16 + c) * 64 +
                                     ((kk2 * 4 + g) ^ swc) * 8];
#pragma unroll
      for (int ni = 0; ni < 8; ++ni) {
        const bf16x8 vf =
            *(const bf16x8*)&Vc[(ni * 16 + c) * 64 + ((kk2 * 4 + g) ^ swc) * 8];
        o[0][ni] = __builtin_amdgcn_mfma_f32_16x16x32_bf16(vf, pf[0], o[0][ni], 0, 0, 0);
        o[1][ni] = __builtin_amdgcn_mfma_f32_16x16x32_bf16(vf, pf[1], o[1][ni], 0, 0, 0);
      }
    }
    __builtin_amdgcn_s_setprio(0);

    __syncthreads();  // buf^1 writes visible, buf readers done
    cur ^= 1;
  }

  // epilogue: complete L across g-groups, normalize, store O rows
  const int b = bh >> 4, h = bh & 15;
#pragma unroll
  for (int mi = 0; mi < 2; ++mi) {
    float s = L[mi];
    s += __shfl_xor(s, 16);
    s += __shfl_xor(s, 32);
    const float inv = 1.0f / s;
    const int q = q0 + wid * 32 + mi * 16 + c;
    unsigned short* orow = Og + (size_t)(b * SEQ + q) * DIMN + h * HD;
#pragma unroll
    for (int ni = 0; ni < 8; ++ni) {
      ushort4 pk;
      pk.x = f2bf(o[mi][ni][0] * inv);
      pk.y = f2bf(o[mi][ni][1] * inv);
      pk.z = f2bf(o[mi][ni][2] * inv);
      pk.w = f2bf(o[mi][ni][3] * inv);
      *(ushort4*)&orow[ni * 16 + g * 4] = pk;
    }
  }
}

// ---------------- launch ----------------
extern "C" void kernel_launch(void* const* d_in, const int* in_sizes, int n_in,
                              void* d_out, int out_size, void* d_ws, size_t ws_size,
                              hipStream_t stream) {
  (void)in_sizes; (void)n_in; (void)out_size; (void)ws_size;
  const float* x  = (const float*)d_in[0];
  const float* wq = (const float*)d_in[1];
  const float* wk = (const float*)d_in[2];
  const float* wv = (const float*)d_in[3];
  const float* wo = (const float*)d_in[4];
  float* out = (float*)d_out;

  // workspace layout (bf16 elems); total ~112 MB
  unsigned short* xb  = (unsigned short*)d_ws;          // 4096x2048
  unsigned short* wqb = xb  + (size_t)8388608;          // 2048x2048 each, contiguous
  unsigned short* wkb = wqb + (size_t)4194304;
  unsigned short* wvb = wkb + (size_t)4194304;
  unsigned short* wob = wvb + (size_t)4194304;
  unsigned short* Qb  = wob + (size_t)4194304;          // (B,H,S,D)
  unsigned short* Kb  = Qb  + (size_t)8388608;          // (B,H,S,D)
  unsigned short* Vt  = Kb  + (size_t)8388608;          // (B,H,D,S)
  unsigned short* Ab  = Vt  + (size_t)8388608;          // (B*S, DIM)

  cast_all_kernel<<<dim3(512, 6), dim3(256), 0, stream>>>(x, wq, wk, wv, wo, xb);

  gemm_qkv_kernel<<<dim3(16, 32, 3), dim3(256), 0, stream>>>(xb, wqb, wkb, wvb, Qb, Kb, Vt);
  attn_kernel<<<dim3(32, 16), dim3(256), 0, stream>>>(Qb, Kb, Vt, Ab);
  gemm_out_kernel<<<dim3(16, 32), dim3(256), 0, stream>>>(Ab, wob, out);
}